// Round 1
// baseline (6754.887 us; speedup 1.0000x reference)
//
#include <hip/hip_runtime.h>

#define NPIX (512 * 512)
#define BLK 256

constexpr float ALPHA_B = 32.0f / 33.0f;   // 1/(1+2^-5)
constexpr float ALPHA_S = 0.8f;            // 1/(1+2^-2)
constexpr float BI_COMPAT = 10.0f;
constexpr float SP_COMPAT = 3.0f;

__device__ __forceinline__ float4 f4zero() { return make_float4(0.f, 0.f, 0.f, 0.f); }

__global__ void k_softmax_init(const float4* __restrict__ u, float4* __restrict__ Q) {
    int n = blockIdx.x * BLK + threadIdx.x;
    if (n >= NPIX) return;
    float4 uu = u[n];
    float l0 = -uu.x, l1 = -uu.y, l2 = -uu.z, l3 = -uu.w;
    float m = fmaxf(fmaxf(l0, l1), fmaxf(l2, l3));
    float e0 = expf(l0 - m), e1 = expf(l1 - m), e2 = expf(l2 - m), e3 = expf(l3 - m);
    float inv = 1.0f / (e0 + e1 + e2 + e3);
    Q[n] = make_float4(e0 * inv, e1 * inv, e2 * inv, e3 * inv);
}

template <int D1>
__global__ void k_splat1(const float* __restrict__ ws, const int* __restrict__ os,
                         float* __restrict__ table) {
    int n = blockIdx.x * BLK + threadIdx.x;
    if (n >= NPIX) return;
#pragma unroll
    for (int r = 0; r < D1; r++) {
        atomicAdd(&table[os[n * D1 + r]], ws[n * D1 + r]);
    }
}

template <int D1>
__global__ void k_splat4(const float4* __restrict__ Q, const float* __restrict__ ws,
                         const int* __restrict__ os, float* __restrict__ table) {
    int n = blockIdx.x * BLK + threadIdx.x;
    if (n >= NPIX) return;
    float4 q = Q[n];
#pragma unroll
    for (int r = 0; r < D1; r++) {
        float w = ws[n * D1 + r];
        int o = os[n * D1 + r];
        float* t = table + 4 * (size_t)o;
        atomicAdd(t + 0, q.x * w);
        atomicAdd(t + 1, q.y * w);
        atomicAdd(t + 2, q.z * w);
        atomicAdd(t + 3, q.w * w);
    }
}

__global__ void k_blur1(const float* __restrict__ in, float* __restrict__ out,
                        const int* __restrict__ bn, int M) {
    int i = blockIdx.x * BLK + threadIdx.x;
    if (i > M) return;
    if (i == 0) { out[0] = 0.f; return; }
    int n1 = bn[(size_t)(i - 1) * 2 + 0];
    int n2 = bn[(size_t)(i - 1) * 2 + 1];
    out[i] = in[i] + 0.5f * (in[n1] + in[n2]);
}

__global__ void k_blur4(const float4* __restrict__ in, float4* __restrict__ out,
                        const int* __restrict__ bn, int M) {
    int i = blockIdx.x * BLK + threadIdx.x;
    if (i > M) return;
    if (i == 0) { out[0] = f4zero(); return; }
    int n1 = bn[(size_t)(i - 1) * 2 + 0];
    int n2 = bn[(size_t)(i - 1) * 2 + 1];
    float4 a = in[i], b = in[n1], c = in[n2];
    out[i] = make_float4(a.x + 0.5f * (b.x + c.x),
                         a.y + 0.5f * (b.y + c.y),
                         a.z + 0.5f * (b.z + c.z),
                         a.w + 0.5f * (b.w + c.w));
}

template <int D1>
__global__ void k_norm_slice(const float* __restrict__ table, const float* __restrict__ ws,
                             const int* __restrict__ os, float alpha,
                             float* __restrict__ inv_out) {
    int n = blockIdx.x * BLK + threadIdx.x;
    if (n >= NPIX) return;
    float s = 0.f;
#pragma unroll
    for (int r = 0; r < D1; r++) {
        s += ws[n * D1 + r] * table[os[n * D1 + r]];
    }
    inv_out[n] = 1.0f / (alpha * s + 1e-20f);
}

__global__ void k_slice_combine(const float4* __restrict__ u,
                                const float4* __restrict__ tb, const float* __restrict__ wsb,
                                const int* __restrict__ osb,
                                const float4* __restrict__ ts, const float* __restrict__ wss,
                                const int* __restrict__ oss,
                                const float* __restrict__ inv_nb,
                                const float* __restrict__ inv_ns,
                                float4* __restrict__ Qout) {
    int n = blockIdx.x * BLK + threadIdx.x;
    if (n >= NPIX) return;
    float4 ab = f4zero();
#pragma unroll
    for (int r = 0; r < 6; r++) {
        float w = wsb[n * 6 + r];
        float4 t = tb[osb[n * 6 + r]];
        ab.x += w * t.x; ab.y += w * t.y; ab.z += w * t.z; ab.w += w * t.w;
    }
    float4 as = f4zero();
#pragma unroll
    for (int r = 0; r < 3; r++) {
        float w = wss[n * 3 + r];
        float4 t = ts[oss[n * 3 + r]];
        as.x += w * t.x; as.y += w * t.y; as.z += w * t.z; as.w += w * t.w;
    }
    float cb = BI_COMPAT * ALPHA_B * inv_nb[n];
    float cs = SP_COMPAT * ALPHA_S * inv_ns[n];
    float4 uu = u[n];
    float l0 = -uu.x + cb * ab.x + cs * as.x;
    float l1 = -uu.y + cb * ab.y + cs * as.y;
    float l2 = -uu.z + cb * ab.z + cs * as.z;
    float l3 = -uu.w + cb * ab.w + cs * as.w;
    float m = fmaxf(fmaxf(l0, l1), fmaxf(l2, l3));
    float e0 = expf(l0 - m), e1 = expf(l1 - m), e2 = expf(l2 - m), e3 = expf(l3 - m);
    float inv = 1.0f / (e0 + e1 + e2 + e3);
    Qout[n] = make_float4(e0 * inv, e1 * inv, e2 * inv, e3 * inv);
}

extern "C" void kernel_launch(void* const* d_in, const int* in_sizes, int n_in,
                              void* d_out, int out_size, void* d_ws, size_t ws_size,
                              hipStream_t stream) {
    const float* unary = (const float*)d_in[0];
    const float* wsb   = (const float*)d_in[1];
    const int*   osb   = (const int*)d_in[2];
    const int*   bnb   = (const int*)d_in[3];
    const float* wss   = (const float*)d_in[5];
    const int*   oss   = (const int*)d_in[6];
    const int*   bns   = (const int*)d_in[7];
    const int Mb = in_sizes[3] / 12;   // bn_b is (6, Mb, 2)
    const int Ms = in_sizes[7] / 6;    // bn_s is (3, Ms, 2)

    float* Q = (float*)d_out;  // N x 4, final value IS the output

    char* p = (char*)d_ws;
    auto alloc = [&](size_t nfloats) -> float* {
        float* r = (float*)p;
        p += nfloats * sizeof(float);
        return r;
    };
    float* tAb = alloc((size_t)(Mb + 1) * 4);
    float* tBb = alloc((size_t)(Mb + 1) * 4);
    float* tAs = alloc((size_t)(Ms + 1) * 4);
    float* tBs = alloc((size_t)(Ms + 1) * 4);
    float* inv_nb = alloc(NPIX);
    float* inv_ns = alloc(NPIX);

    dim3 blk(BLK);
    dim3 gN((NPIX + BLK - 1) / BLK);
    dim3 gMb((Mb + 1 + BLK - 1) / BLK);
    dim3 gMs((Ms + 1 + BLK - 1) / BLK);

    // ---- normalizers (C=1 filter on ones), reuse table buffers as scratch ----
    hipMemsetAsync(tAb, 0, (size_t)(Mb + 1) * sizeof(float), stream);
    k_splat1<6><<<gN, blk, 0, stream>>>(wsb, osb, tAb);
    {
        float* a = tAb; float* b = tBb;
        for (int j = 0; j < 6; j++) {
            k_blur1<<<gMb, blk, 0, stream>>>(a, b, bnb + (size_t)j * Mb * 2, Mb);
            float* t = a; a = b; b = t;
        }
        k_norm_slice<6><<<gN, blk, 0, stream>>>(a, wsb, osb, ALPHA_B, inv_nb);
    }
    hipMemsetAsync(tAs, 0, (size_t)(Ms + 1) * sizeof(float), stream);
    k_splat1<3><<<gN, blk, 0, stream>>>(wss, oss, tAs);
    {
        float* a = tAs; float* b = tBs;
        for (int j = 0; j < 3; j++) {
            k_blur1<<<gMs, blk, 0, stream>>>(a, b, bns + (size_t)j * Ms * 2, Ms);
            float* t = a; a = b; b = t;
        }
        k_norm_slice<3><<<gN, blk, 0, stream>>>(a, wss, oss, ALPHA_S, inv_ns);
    }

    // ---- Q0 = softmax(-u) ----
    k_softmax_init<<<gN, blk, 0, stream>>>((const float4*)unary, (float4*)Q);

    // ---- 10 mean-field iterations ----
    for (int it = 0; it < 10; it++) {
        // bilateral filter of Q
        hipMemsetAsync(tAb, 0, (size_t)(Mb + 1) * 4 * sizeof(float), stream);
        k_splat4<6><<<gN, blk, 0, stream>>>((const float4*)Q, wsb, osb, tAb);
        float* a = tAb; float* b = tBb;
        for (int j = 0; j < 6; j++) {
            k_blur4<<<gMb, blk, 0, stream>>>((const float4*)a, (float4*)b,
                                             bnb + (size_t)j * Mb * 2, Mb);
            float* t = a; a = b; b = t;
        }
        float* finb = a;  // after 6 swaps -> tAb

        // spatial filter of Q
        hipMemsetAsync(tAs, 0, (size_t)(Ms + 1) * 4 * sizeof(float), stream);
        k_splat4<3><<<gN, blk, 0, stream>>>((const float4*)Q, wss, oss, tAs);
        float* as_ = tAs; float* bs_ = tBs;
        for (int j = 0; j < 3; j++) {
            k_blur4<<<gMs, blk, 0, stream>>>((const float4*)as_, (float4*)bs_,
                                             bns + (size_t)j * Ms * 2, Ms);
            float* t = as_; as_ = bs_; bs_ = t;
        }
        float* fins = as_;  // after 3 swaps -> tBs

        // fused slice + message + softmax (writes Q in-place; Q == d_out)
        k_slice_combine<<<gN, blk, 0, stream>>>((const float4*)unary,
                                                (const float4*)finb, wsb, osb,
                                                (const float4*)fins, wss, oss,
                                                inv_nb, inv_ns, (float4*)Q);
    }
}

// Round 2
// 1355.706 us; speedup vs baseline: 4.9826x; 4.9826x over previous
//
#include <hip/hip_runtime.h>

#define NPIX (512 * 512)
#define BLK 256

#define SCAN_T 256
#define SCAN_E 8
#define SCAN_CHUNK (SCAN_T * SCAN_E)  // 2048

constexpr float ALPHA_B = 32.0f / 33.0f;   // 1/(1+2^-5)
constexpr float ALPHA_S = 0.8f;            // 1/(1+2^-2)
constexpr float BI_COMPAT = 10.0f;
constexpr float SP_COMPAT = 3.0f;

__device__ __forceinline__ float4 f4zero() { return make_float4(0.f, 0.f, 0.f, 0.f); }

// ---------------- softmax init ----------------
__global__ void k_softmax_init(const float4* __restrict__ u, float4* __restrict__ Q) {
    int n = blockIdx.x * BLK + threadIdx.x;
    if (n >= NPIX) return;
    float4 uu = u[n];
    float l0 = -uu.x, l1 = -uu.y, l2 = -uu.z, l3 = -uu.w;
    float m = fmaxf(fmaxf(l0, l1), fmaxf(l2, l3));
    float e0 = expf(l0 - m), e1 = expf(l1 - m), e2 = expf(l2 - m), e3 = expf(l3 - m);
    float inv = 1.0f / (e0 + e1 + e2 + e3);
    Q[n] = make_float4(e0 * inv, e1 * inv, e2 * inv, e3 * inv);
}

// ---------------- CSR index build ----------------
template <int D1>
__global__ void k_count(const int* __restrict__ os, int* __restrict__ counts) {
    int n = blockIdx.x * BLK + threadIdx.x;
    if (n >= NPIX) return;
#pragma unroll
    for (int r = 0; r < D1; r++) atomicAdd(&counts[os[n * D1 + r]], 1);
}

__global__ void k_chunk_sum(const int* __restrict__ counts, int V, int* __restrict__ csum) {
    __shared__ int lds[SCAN_T];
    int base = blockIdx.x * SCAN_CHUNK;
    int s = 0;
#pragma unroll
    for (int j = 0; j < SCAN_E; j++) {
        int idx = base + threadIdx.x * SCAN_E + j;
        if (idx < V) s += counts[idx];
    }
    lds[threadIdx.x] = s;
    __syncthreads();
    for (int off = SCAN_T / 2; off > 0; off >>= 1) {
        if ((int)threadIdx.x < off) lds[threadIdx.x] += lds[threadIdx.x + off];
        __syncthreads();
    }
    if (threadIdx.x == 0) csum[blockIdx.x] = lds[0];
}

__global__ void k_scan_csum(int* __restrict__ csum, int nchunks) {
    __shared__ int lds[SCAN_T];
    int carry = 0;
    for (int base = 0; base < nchunks; base += SCAN_T) {
        int idx = base + threadIdx.x;
        int v = (idx < nchunks) ? csum[idx] : 0;
        lds[threadIdx.x] = v;
        __syncthreads();
        for (int off = 1; off < SCAN_T; off <<= 1) {
            int t = ((int)threadIdx.x >= off) ? lds[threadIdx.x - off] : 0;
            __syncthreads();
            lds[threadIdx.x] += t;
            __syncthreads();
        }
        int incl = lds[threadIdx.x];
        int tile_total = lds[SCAN_T - 1];
        if (idx < nchunks) csum[idx] = incl - v + carry;  // exclusive
        carry += tile_total;
        __syncthreads();
    }
}

__global__ void k_chunk_scan(const int* __restrict__ counts, int V,
                             const int* __restrict__ csum, int* __restrict__ start) {
    __shared__ int lds[SCAN_T];
    int base = blockIdx.x * SCAN_CHUNK;
    int local[SCAN_E];
    int s = 0;
#pragma unroll
    for (int j = 0; j < SCAN_E; j++) {
        int idx = base + threadIdx.x * SCAN_E + j;
        int c = (idx < V) ? counts[idx] : 0;
        local[j] = c;
        s += c;
    }
    lds[threadIdx.x] = s;
    __syncthreads();
    for (int off = 1; off < SCAN_T; off <<= 1) {
        int t = ((int)threadIdx.x >= off) ? lds[threadIdx.x - off] : 0;
        __syncthreads();
        lds[threadIdx.x] += t;
        __syncthreads();
    }
    int excl = lds[threadIdx.x] - s + csum[blockIdx.x];
#pragma unroll
    for (int j = 0; j < SCAN_E; j++) {
        int idx = base + threadIdx.x * SCAN_E + j;
        if (idx < V) start[idx] = excl;
        excl += local[j];
    }
}

template <int D1>
__global__ void k_fill(const int* __restrict__ os, const float* __restrict__ ws,
                       int* __restrict__ cursor, int2* __restrict__ entries) {
    int n = blockIdx.x * BLK + threadIdx.x;
    if (n >= NPIX) return;
#pragma unroll
    for (int r = 0; r < D1; r++) {
        int o = os[n * D1 + r];
        float w = ws[n * D1 + r];
        int pos = atomicAdd(&cursor[o], 1);
        entries[pos] = make_int2(n, __float_as_int(w));
    }
}

// ---------------- gather-based splat ----------------
__global__ void k_gather4(const int2* __restrict__ entries, const int* __restrict__ start,
                          int total, int V, const float4* __restrict__ Q,
                          float4* __restrict__ table) {
    int i = blockIdx.x * BLK + threadIdx.x;
    if (i >= V) return;
    int s = start[i];
    int e = (i + 1 < V) ? start[i + 1] : total;
    float4 acc = f4zero();
    for (int k = s; k < e; k++) {
        int2 en = entries[k];
        float w = __int_as_float(en.y);
        float4 q = Q[en.x];
        acc.x += w * q.x; acc.y += w * q.y; acc.z += w * q.z; acc.w += w * q.w;
    }
    table[i] = acc;  // row 0 has no entries -> stays zero sink
}

__global__ void k_gather1(const int2* __restrict__ entries, const int* __restrict__ start,
                          int total, int V, float* __restrict__ table) {
    int i = blockIdx.x * BLK + threadIdx.x;
    if (i >= V) return;
    int s = start[i];
    int e = (i + 1 < V) ? start[i + 1] : total;
    float acc = 0.f;
    for (int k = s; k < e; k++) acc += __int_as_float(entries[k].y);
    table[i] = acc;
}

// ---------------- atomic splat (fallback) ----------------
template <int D1>
__global__ void k_splat1(const float* __restrict__ ws, const int* __restrict__ os,
                         float* __restrict__ table) {
    int n = blockIdx.x * BLK + threadIdx.x;
    if (n >= NPIX) return;
#pragma unroll
    for (int r = 0; r < D1; r++) atomicAdd(&table[os[n * D1 + r]], ws[n * D1 + r]);
}

template <int D1>
__global__ void k_splat4(const float4* __restrict__ Q, const float* __restrict__ ws,
                         const int* __restrict__ os, float* __restrict__ table) {
    int n = blockIdx.x * BLK + threadIdx.x;
    if (n >= NPIX) return;
    float4 q = Q[n];
#pragma unroll
    for (int r = 0; r < D1; r++) {
        float w = ws[n * D1 + r];
        int o = os[n * D1 + r];
        float* t = table + 4 * (size_t)o;
        atomicAdd(t + 0, q.x * w);
        atomicAdd(t + 1, q.y * w);
        atomicAdd(t + 2, q.z * w);
        atomicAdd(t + 3, q.w * w);
    }
}

// ---------------- blur ----------------
__global__ void k_blur1(const float* __restrict__ in, float* __restrict__ out,
                        const int* __restrict__ bn, int M) {
    int i = blockIdx.x * BLK + threadIdx.x;
    if (i > M) return;
    if (i == 0) { out[0] = 0.f; return; }
    int n1 = bn[(size_t)(i - 1) * 2 + 0];
    int n2 = bn[(size_t)(i - 1) * 2 + 1];
    out[i] = in[i] + 0.5f * (in[n1] + in[n2]);
}

__global__ void k_blur4(const float4* __restrict__ in, float4* __restrict__ out,
                        const int* __restrict__ bn, int M) {
    int i = blockIdx.x * BLK + threadIdx.x;
    if (i > M) return;
    if (i == 0) { out[0] = f4zero(); return; }
    int n1 = bn[(size_t)(i - 1) * 2 + 0];
    int n2 = bn[(size_t)(i - 1) * 2 + 1];
    float4 a = in[i], b = in[n1], c = in[n2];
    out[i] = make_float4(a.x + 0.5f * (b.x + c.x),
                         a.y + 0.5f * (b.y + c.y),
                         a.z + 0.5f * (b.z + c.z),
                         a.w + 0.5f * (b.w + c.w));
}

// ---------------- slice ----------------
template <int D1>
__global__ void k_norm_slice(const float* __restrict__ table, const float* __restrict__ ws,
                             const int* __restrict__ os, float alpha,
                             float* __restrict__ inv_out) {
    int n = blockIdx.x * BLK + threadIdx.x;
    if (n >= NPIX) return;
    float s = 0.f;
#pragma unroll
    for (int r = 0; r < D1; r++) s += ws[n * D1 + r] * table[os[n * D1 + r]];
    inv_out[n] = 1.0f / (alpha * s + 1e-20f);
}

__global__ void k_slice_combine(const float4* __restrict__ u,
                                const float4* __restrict__ tb, const float* __restrict__ wsb,
                                const int* __restrict__ osb,
                                const float4* __restrict__ ts, const float* __restrict__ wss,
                                const int* __restrict__ oss,
                                const float* __restrict__ inv_nb,
                                const float* __restrict__ inv_ns,
                                float4* __restrict__ Qout) {
    int n = blockIdx.x * BLK + threadIdx.x;
    if (n >= NPIX) return;
    float4 ab = f4zero();
#pragma unroll
    for (int r = 0; r < 6; r++) {
        float w = wsb[n * 6 + r];
        float4 t = tb[osb[n * 6 + r]];
        ab.x += w * t.x; ab.y += w * t.y; ab.z += w * t.z; ab.w += w * t.w;
    }
    float4 as = f4zero();
#pragma unroll
    for (int r = 0; r < 3; r++) {
        float w = wss[n * 3 + r];
        float4 t = ts[oss[n * 3 + r]];
        as.x += w * t.x; as.y += w * t.y; as.z += w * t.z; as.w += w * t.w;
    }
    float cb = BI_COMPAT * ALPHA_B * inv_nb[n];
    float cs = SP_COMPAT * ALPHA_S * inv_ns[n];
    float4 uu = u[n];
    float l0 = -uu.x + cb * ab.x + cs * as.x;
    float l1 = -uu.y + cb * ab.y + cs * as.y;
    float l2 = -uu.z + cb * ab.z + cs * as.z;
    float l3 = -uu.w + cb * ab.w + cs * as.w;
    float m = fmaxf(fmaxf(l0, l1), fmaxf(l2, l3));
    float e0 = expf(l0 - m), e1 = expf(l1 - m), e2 = expf(l2 - m), e3 = expf(l3 - m);
    float inv = 1.0f / (e0 + e1 + e2 + e3);
    Qout[n] = make_float4(e0 * inv, e1 * inv, e2 * inv, e3 * inv);
}

extern "C" void kernel_launch(void* const* d_in, const int* in_sizes, int n_in,
                              void* d_out, int out_size, void* d_ws, size_t ws_size,
                              hipStream_t stream) {
    const float* unary = (const float*)d_in[0];
    const float* wsb   = (const float*)d_in[1];
    const int*   osb   = (const int*)d_in[2];
    const int*   bnb   = (const int*)d_in[3];
    const float* wss   = (const float*)d_in[5];
    const int*   oss   = (const int*)d_in[6];
    const int*   bns   = (const int*)d_in[7];
    const int Mb = in_sizes[3] / 12;   // bn_b is (6, Mb, 2)
    const int Ms = in_sizes[7] / 6;    // bn_s is (3, Ms, 2)
    const int Vb = Mb + 1, Vs = Ms + 1;
    const int totB = NPIX * 6, totS = NPIX * 3;

    float* Q = (float*)d_out;  // N x 4, final value IS the output

    char* p = (char*)d_ws;
    auto alloc = [&](size_t nbytes) -> void* {
        void* r = (void*)p;
        p += (nbytes + 15) & ~(size_t)15;
        return r;
    };
    float* tAb = (float*)alloc((size_t)Vb * 4 * sizeof(float));
    float* tBb = (float*)alloc((size_t)Vb * 4 * sizeof(float));
    float* tAs = (float*)alloc((size_t)Vs * 4 * sizeof(float));
    float* tBs = (float*)alloc((size_t)Vs * 4 * sizeof(float));
    float* inv_nb = (float*)alloc(NPIX * sizeof(float));
    float* inv_ns = (float*)alloc(NPIX * sizeof(float));
    int*  startB  = (int*)alloc((size_t)Vb * sizeof(int));
    int*  cursorB = (int*)alloc((size_t)Vb * sizeof(int));
    int2* entB    = (int2*)alloc((size_t)totB * sizeof(int2));
    int*  startS  = (int*)alloc((size_t)Vs * sizeof(int));
    int*  cursorS = (int*)alloc((size_t)Vs * sizeof(int));
    int2* entS    = (int2*)alloc((size_t)totS * sizeof(int2));
    int*  csum    = (int*)alloc(8192 * sizeof(int));
    size_t need = (size_t)(p - (char*)d_ws);
    bool use_gather = need <= ws_size;

    dim3 blk(BLK);
    dim3 gN((NPIX + BLK - 1) / BLK);
    dim3 gMb((Mb + 1 + BLK - 1) / BLK);
    dim3 gMs((Ms + 1 + BLK - 1) / BLK);
    dim3 gVb((Vb + BLK - 1) / BLK);
    dim3 gVs((Vs + BLK - 1) / BLK);

    if (use_gather) {
        // ---- build CSR inverted index: bilateral ----
        int nchB = (Vb + SCAN_CHUNK - 1) / SCAN_CHUNK;
        hipMemsetAsync(cursorB, 0, (size_t)Vb * sizeof(int), stream);  // use as counts
        k_count<6><<<gN, blk, 0, stream>>>(osb, cursorB);
        k_chunk_sum<<<dim3(nchB), dim3(SCAN_T), 0, stream>>>(cursorB, Vb, csum);
        k_scan_csum<<<dim3(1), dim3(SCAN_T), 0, stream>>>(csum, nchB);
        k_chunk_scan<<<dim3(nchB), dim3(SCAN_T), 0, stream>>>(cursorB, Vb, csum, startB);
        hipMemcpyAsync(cursorB, startB, (size_t)Vb * sizeof(int),
                       hipMemcpyDeviceToDevice, stream);
        k_fill<6><<<gN, blk, 0, stream>>>(osb, wsb, cursorB, entB);

        // ---- build CSR inverted index: spatial ----
        int nchS = (Vs + SCAN_CHUNK - 1) / SCAN_CHUNK;
        hipMemsetAsync(cursorS, 0, (size_t)Vs * sizeof(int), stream);
        k_count<3><<<gN, blk, 0, stream>>>(oss, cursorS);
        k_chunk_sum<<<dim3(nchS), dim3(SCAN_T), 0, stream>>>(cursorS, Vs, csum);
        k_scan_csum<<<dim3(1), dim3(SCAN_T), 0, stream>>>(csum, nchS);
        k_chunk_scan<<<dim3(nchS), dim3(SCAN_T), 0, stream>>>(cursorS, Vs, csum, startS);
        hipMemcpyAsync(cursorS, startS, (size_t)Vs * sizeof(int),
                       hipMemcpyDeviceToDevice, stream);
        k_fill<3><<<gN, blk, 0, stream>>>(oss, wss, cursorS, entS);

        // ---- normalizers ----
        k_gather1<<<gVb, blk, 0, stream>>>(entB, startB, totB, Vb, tAb);
        {
            float* a = tAb; float* b = tBb;
            for (int j = 0; j < 6; j++) {
                k_blur1<<<gMb, blk, 0, stream>>>(a, b, bnb + (size_t)j * Mb * 2, Mb);
                float* t = a; a = b; b = t;
            }
            k_norm_slice<6><<<gN, blk, 0, stream>>>(a, wsb, osb, ALPHA_B, inv_nb);
        }
        k_gather1<<<gVs, blk, 0, stream>>>(entS, startS, totS, Vs, tAs);
        {
            float* a = tAs; float* b = tBs;
            for (int j = 0; j < 3; j++) {
                k_blur1<<<gMs, blk, 0, stream>>>(a, b, bns + (size_t)j * Ms * 2, Ms);
                float* t = a; a = b; b = t;
            }
            k_norm_slice<3><<<gN, blk, 0, stream>>>(a, wss, oss, ALPHA_S, inv_ns);
        }

        k_softmax_init<<<gN, blk, 0, stream>>>((const float4*)unary, (float4*)Q);

        for (int it = 0; it < 10; it++) {
            k_gather4<<<gVb, blk, 0, stream>>>(entB, startB, totB, Vb,
                                               (const float4*)Q, (float4*)tAb);
            float* a = tAb; float* b = tBb;
            for (int j = 0; j < 6; j++) {
                k_blur4<<<gMb, blk, 0, stream>>>((const float4*)a, (float4*)b,
                                                 bnb + (size_t)j * Mb * 2, Mb);
                float* t = a; a = b; b = t;
            }
            float* finb = a;

            k_gather4<<<gVs, blk, 0, stream>>>(entS, startS, totS, Vs,
                                               (const float4*)Q, (float4*)tAs);
            float* as_ = tAs; float* bs_ = tBs;
            for (int j = 0; j < 3; j++) {
                k_blur4<<<gMs, blk, 0, stream>>>((const float4*)as_, (float4*)bs_,
                                                 bns + (size_t)j * Ms * 2, Ms);
                float* t = as_; as_ = bs_; bs_ = t;
            }
            float* fins = as_;

            k_slice_combine<<<gN, blk, 0, stream>>>((const float4*)unary,
                                                    (const float4*)finb, wsb, osb,
                                                    (const float4*)fins, wss, oss,
                                                    inv_nb, inv_ns, (float4*)Q);
        }
    } else {
        // ---- fallback: atomic splat path (R0 behavior) ----
        hipMemsetAsync(tAb, 0, (size_t)Vb * sizeof(float), stream);
        k_splat1<6><<<gN, blk, 0, stream>>>(wsb, osb, tAb);
        {
            float* a = tAb; float* b = tBb;
            for (int j = 0; j < 6; j++) {
                k_blur1<<<gMb, blk, 0, stream>>>(a, b, bnb + (size_t)j * Mb * 2, Mb);
                float* t = a; a = b; b = t;
            }
            k_norm_slice<6><<<gN, blk, 0, stream>>>(a, wsb, osb, ALPHA_B, inv_nb);
        }
        hipMemsetAsync(tAs, 0, (size_t)Vs * sizeof(float), stream);
        k_splat1<3><<<gN, blk, 0, stream>>>(wss, oss, tAs);
        {
            float* a = tAs; float* b = tBs;
            for (int j = 0; j < 3; j++) {
                k_blur1<<<gMs, blk, 0, stream>>>(a, b, bns + (size_t)j * Ms * 2, Ms);
                float* t = a; a = b; b = t;
            }
            k_norm_slice<3><<<gN, blk, 0, stream>>>(a, wss, oss, ALPHA_S, inv_ns);
        }
        k_softmax_init<<<gN, blk, 0, stream>>>((const float4*)unary, (float4*)Q);
        for (int it = 0; it < 10; it++) {
            hipMemsetAsync(tAb, 0, (size_t)Vb * 4 * sizeof(float), stream);
            k_splat4<6><<<gN, blk, 0, stream>>>((const float4*)Q, wsb, osb, tAb);
            float* a = tAb; float* b = tBb;
            for (int j = 0; j < 6; j++) {
                k_blur4<<<gMb, blk, 0, stream>>>((const float4*)a, (float4*)b,
                                                 bnb + (size_t)j * Mb * 2, Mb);
                float* t = a; a = b; b = t;
            }
            float* finb = a;
            hipMemsetAsync(tAs, 0, (size_t)Vs * 4 * sizeof(float), stream);
            k_splat4<3><<<gN, blk, 0, stream>>>((const float4*)Q, wss, oss, tAs);
            float* as_ = tAs; float* bs_ = tBs;
            for (int j = 0; j < 3; j++) {
                k_blur4<<<gMs, blk, 0, stream>>>((const float4*)as_, (float4*)bs_,
                                                 bns + (size_t)j * Ms * 2, Ms);
                float* t = as_; as_ = bs_; bs_ = t;
            }
            float* fins = as_;
            k_slice_combine<<<gN, blk, 0, stream>>>((const float4*)unary,
                                                    (const float4*)finb, wsb, osb,
                                                    (const float4*)fins, wss, oss,
                                                    inv_nb, inv_ns, (float4*)Q);
        }
    }
}

// Round 3
// 1100.183 us; speedup vs baseline: 6.1398x; 1.2323x over previous
//
#include <hip/hip_runtime.h>

#define NPIX (512 * 512)
#define BLK 256

#define SCAN_T 256
#define SCAN_E 8
#define SCAN_CHUNK (SCAN_T * SCAN_E)  // 2048

typedef _Float16 h4 __attribute__((ext_vector_type(4)));

constexpr float ALPHA_B = 32.0f / 33.0f;   // 1/(1+2^-5)
constexpr float ALPHA_S = 0.8f;            // 1/(1+2^-2)
constexpr float BI_COMPAT = 10.0f;
constexpr float SP_COMPAT = 3.0f;

__device__ __forceinline__ float4 f4zero() { return make_float4(0.f, 0.f, 0.f, 0.f); }
__device__ __forceinline__ h4 h4zero() {
    h4 z; z.x = (_Float16)0.f; z.y = (_Float16)0.f; z.z = (_Float16)0.f; z.w = (_Float16)0.f;
    return z;
}

// ---------------- softmax init ----------------
__global__ void k_softmax_init(const float4* __restrict__ u, float4* __restrict__ Q) {
    int n = blockIdx.x * BLK + threadIdx.x;
    if (n >= NPIX) return;
    float4 uu = u[n];
    float l0 = -uu.x, l1 = -uu.y, l2 = -uu.z, l3 = -uu.w;
    float m = fmaxf(fmaxf(l0, l1), fmaxf(l2, l3));
    float e0 = expf(l0 - m), e1 = expf(l1 - m), e2 = expf(l2 - m), e3 = expf(l3 - m);
    float inv = 1.0f / (e0 + e1 + e2 + e3);
    Q[n] = make_float4(e0 * inv, e1 * inv, e2 * inv, e3 * inv);
}

// ---------------- CSR index build ----------------
__global__ void k_count_both(const int* __restrict__ osb, const int* __restrict__ oss,
                             int* __restrict__ cntB, int* __restrict__ cntS) {
    int n = blockIdx.x * BLK + threadIdx.x;
    if (n >= NPIX) return;
#pragma unroll
    for (int r = 0; r < 6; r++) atomicAdd(&cntB[osb[n * 6 + r]], 1);
#pragma unroll
    for (int r = 0; r < 3; r++) atomicAdd(&cntS[oss[n * 3 + r]], 1);
}

__global__ void k_chunk_sum(const int* __restrict__ counts, int V, int* __restrict__ csum) {
    __shared__ int lds[SCAN_T];
    int base = blockIdx.x * SCAN_CHUNK;
    int s = 0;
#pragma unroll
    for (int j = 0; j < SCAN_E; j++) {
        int idx = base + threadIdx.x * SCAN_E + j;
        if (idx < V) s += counts[idx];
    }
    lds[threadIdx.x] = s;
    __syncthreads();
    for (int off = SCAN_T / 2; off > 0; off >>= 1) {
        if ((int)threadIdx.x < off) lds[threadIdx.x] += lds[threadIdx.x + off];
        __syncthreads();
    }
    if (threadIdx.x == 0) csum[blockIdx.x] = lds[0];
}

__global__ void k_scan_csum(int* __restrict__ csum, int nchunks) {
    __shared__ int lds[SCAN_T];
    int carry = 0;
    for (int base = 0; base < nchunks; base += SCAN_T) {
        int idx = base + threadIdx.x;
        int v = (idx < nchunks) ? csum[idx] : 0;
        lds[threadIdx.x] = v;
        __syncthreads();
        for (int off = 1; off < SCAN_T; off <<= 1) {
            int t = ((int)threadIdx.x >= off) ? lds[threadIdx.x - off] : 0;
            __syncthreads();
            lds[threadIdx.x] += t;
            __syncthreads();
        }
        int incl = lds[threadIdx.x];
        int tile_total = lds[SCAN_T - 1];
        if (idx < nchunks) csum[idx] = incl - v + carry;  // exclusive
        carry += tile_total;
        __syncthreads();
    }
}

// writes BOTH start[] and cursor[] (saves a 5 MB d2d memcpy)
__global__ void k_chunk_scan(const int* __restrict__ counts, int V,
                             const int* __restrict__ csum, int* __restrict__ start,
                             int* __restrict__ cursor) {
    __shared__ int lds[SCAN_T];
    int base = blockIdx.x * SCAN_CHUNK;
    int local[SCAN_E];
    int s = 0;
#pragma unroll
    for (int j = 0; j < SCAN_E; j++) {
        int idx = base + threadIdx.x * SCAN_E + j;
        int c = (idx < V) ? counts[idx] : 0;
        local[j] = c;
        s += c;
    }
    lds[threadIdx.x] = s;
    __syncthreads();
    for (int off = 1; off < SCAN_T; off <<= 1) {
        int t = ((int)threadIdx.x >= off) ? lds[threadIdx.x - off] : 0;
        __syncthreads();
        lds[threadIdx.x] += t;
        __syncthreads();
    }
    int excl = lds[threadIdx.x] - s + csum[blockIdx.x];
#pragma unroll
    for (int j = 0; j < SCAN_E; j++) {
        int idx = base + threadIdx.x * SCAN_E + j;
        if (idx < V) { start[idx] = excl; cursor[idx] = excl; }
        excl += local[j];
    }
}

__global__ void k_fill_both(const int* __restrict__ osb, const float* __restrict__ wsb,
                            int* __restrict__ curB, int2* __restrict__ entB,
                            const int* __restrict__ oss, const float* __restrict__ wss,
                            int* __restrict__ curS, int2* __restrict__ entS) {
    int n = blockIdx.x * BLK + threadIdx.x;
    if (n >= NPIX) return;
#pragma unroll
    for (int r = 0; r < 6; r++) {
        int o = osb[n * 6 + r];
        int pos = atomicAdd(&curB[o], 1);
        entB[pos] = make_int2(n, __float_as_int(wsb[n * 6 + r]));
    }
#pragma unroll
    for (int r = 0; r < 3; r++) {
        int o = oss[n * 3 + r];
        int pos = atomicAdd(&curS[o], 1);
        entS[pos] = make_int2(n, __float_as_int(wss[n * 3 + r]));
    }
}

// ---------------- gather-based splat ----------------
__global__ void k_gather1_both(const int2* __restrict__ entB, const int* __restrict__ startB,
                               int totB, int Vb, float* __restrict__ nB,
                               const int2* __restrict__ entS, const int* __restrict__ startS,
                               int totS, int Vs, float* __restrict__ nS) {
    int i = blockIdx.x * BLK + threadIdx.x;
    const int2* ent; const int* st; int tot, V, idx; float* out;
    if (i < Vb) { ent = entB; st = startB; tot = totB; V = Vb; out = nB; idx = i; }
    else {
        idx = i - Vb;
        if (idx >= Vs) return;
        ent = entS; st = startS; tot = totS; V = Vs; out = nS;
    }
    int s = st[idx];
    int e = (idx + 1 < V) ? st[idx + 1] : tot;
    float acc = 0.f;
    for (int k = s; k < e; k++) acc += __int_as_float(ent[k].y);
    out[idx] = acc;
}

__global__ void k_gather4h_both(const int2* __restrict__ entB, const int* __restrict__ startB,
                                int totB, int Vb, h4* __restrict__ tB,
                                const int2* __restrict__ entS, const int* __restrict__ startS,
                                int totS, int Vs, h4* __restrict__ tS,
                                const float4* __restrict__ Q) {
    int i = blockIdx.x * BLK + threadIdx.x;
    const int2* ent; const int* st; int tot, V, idx; h4* out;
    if (i < Vb) { ent = entB; st = startB; tot = totB; V = Vb; out = tB; idx = i; }
    else {
        idx = i - Vb;
        if (idx >= Vs) return;
        ent = entS; st = startS; tot = totS; V = Vs; out = tS;
    }
    int s = st[idx];
    int e = (idx + 1 < V) ? st[idx + 1] : tot;
    float ax = 0.f, ay = 0.f, az = 0.f, aw = 0.f;
    for (int k = s; k < e; k++) {
        int2 en = ent[k];
        float w = __int_as_float(en.y);
        float4 q = Q[en.x];
        ax += w * q.x; ay += w * q.y; az += w * q.z; aw += w * q.w;
    }
    h4 h;
    h.x = (_Float16)ax; h.y = (_Float16)ay; h.z = (_Float16)az; h.w = (_Float16)aw;
    out[idx] = h;
}

// ---------------- blur ----------------
__global__ void k_blur1(const float* __restrict__ in, float* __restrict__ out,
                        const int* __restrict__ bn, int M) {
    int i = blockIdx.x * BLK + threadIdx.x;
    if (i > M) return;
    if (i == 0) { out[0] = 0.f; return; }
    int n1 = bn[(size_t)(i - 1) * 2 + 0];
    int n2 = bn[(size_t)(i - 1) * 2 + 1];
    out[i] = in[i] + 0.5f * (in[n1] + in[n2]);
}

__global__ void k_blur1_both(const float* __restrict__ inB, float* __restrict__ outB,
                             const int* __restrict__ bnB, int Mb,
                             const float* __restrict__ inS, float* __restrict__ outS,
                             const int* __restrict__ bnS, int Ms) {
    int i = blockIdx.x * BLK + threadIdx.x;
    const float* in; float* out; const int* bn; int M, idx;
    if (i <= Mb) { in = inB; out = outB; bn = bnB; M = Mb; idx = i; }
    else {
        idx = i - (Mb + 1);
        if (idx > Ms) return;
        in = inS; out = outS; bn = bnS; M = Ms;
    }
    if (idx == 0) { out[0] = 0.f; return; }
    int n1 = bn[(size_t)(idx - 1) * 2 + 0];
    int n2 = bn[(size_t)(idx - 1) * 2 + 1];
    out[idx] = in[idx] + 0.5f * (in[n1] + in[n2]);
}

__global__ void k_blur4h(const h4* __restrict__ in, h4* __restrict__ out,
                         const int* __restrict__ bn, int M) {
    int i = blockIdx.x * BLK + threadIdx.x;
    if (i > M) return;
    if (i == 0) { out[0] = h4zero(); return; }
    int n1 = bn[(size_t)(i - 1) * 2 + 0];
    int n2 = bn[(size_t)(i - 1) * 2 + 1];
    h4 a = in[i], b = in[n1], c = in[n2];
    h4 o;
    o.x = (_Float16)((float)a.x + 0.5f * ((float)b.x + (float)c.x));
    o.y = (_Float16)((float)a.y + 0.5f * ((float)b.y + (float)c.y));
    o.z = (_Float16)((float)a.z + 0.5f * ((float)b.z + (float)c.z));
    o.w = (_Float16)((float)a.w + 0.5f * ((float)b.w + (float)c.w));
    out[i] = o;
}

__global__ void k_blur4h_both(const h4* __restrict__ inB, h4* __restrict__ outB,
                              const int* __restrict__ bnB, int Mb,
                              const h4* __restrict__ inS, h4* __restrict__ outS,
                              const int* __restrict__ bnS, int Ms) {
    int i = blockIdx.x * BLK + threadIdx.x;
    const h4* in; h4* out; const int* bn; int M, idx;
    if (i <= Mb) { in = inB; out = outB; bn = bnB; M = Mb; idx = i; }
    else {
        idx = i - (Mb + 1);
        if (idx > Ms) return;
        in = inS; out = outS; bn = bnS; M = Ms;
    }
    if (idx == 0) { out[0] = h4zero(); return; }
    int n1 = bn[(size_t)(idx - 1) * 2 + 0];
    int n2 = bn[(size_t)(idx - 1) * 2 + 1];
    h4 a = in[idx], b = in[n1], c = in[n2];
    h4 o;
    o.x = (_Float16)((float)a.x + 0.5f * ((float)b.x + (float)c.x));
    o.y = (_Float16)((float)a.y + 0.5f * ((float)b.y + (float)c.y));
    o.z = (_Float16)((float)a.z + 0.5f * ((float)b.z + (float)c.z));
    o.w = (_Float16)((float)a.w + 0.5f * ((float)b.w + (float)c.w));
    out[idx] = o;
}

// ---------------- normalizer slice + weight prescale ----------------
__global__ void k_norm_prescale(const float* __restrict__ nTb, const float* __restrict__ wsb,
                                const int* __restrict__ osb,
                                const float* __restrict__ nTs, const float* __restrict__ wss,
                                const int* __restrict__ oss,
                                float* __restrict__ wsbp, float* __restrict__ wssp) {
    int n = blockIdx.x * BLK + threadIdx.x;
    if (n >= NPIX) return;
    float sb = 0.f;
#pragma unroll
    for (int r = 0; r < 6; r++) sb += wsb[n * 6 + r] * nTb[osb[n * 6 + r]];
    float cb = BI_COMPAT * ALPHA_B / (ALPHA_B * sb + 1e-20f);
#pragma unroll
    for (int r = 0; r < 6; r++) wsbp[n * 6 + r] = wsb[n * 6 + r] * cb;
    float ss = 0.f;
#pragma unroll
    for (int r = 0; r < 3; r++) ss += wss[n * 3 + r] * nTs[oss[n * 3 + r]];
    float cs = SP_COMPAT * ALPHA_S / (ALPHA_S * ss + 1e-20f);
#pragma unroll
    for (int r = 0; r < 3; r++) wssp[n * 3 + r] = wss[n * 3 + r] * cs;
}

// ---------------- fused slice + message + softmax ----------------
__global__ void k_slice_combine_h(const float4* __restrict__ u,
                                  const h4* __restrict__ tb, const float* __restrict__ wsbp,
                                  const int* __restrict__ osb,
                                  const h4* __restrict__ ts, const float* __restrict__ wssp,
                                  const int* __restrict__ oss,
                                  float4* __restrict__ Qout) {
    int n = blockIdx.x * BLK + threadIdx.x;
    if (n >= NPIX) return;
    float4 uu = u[n];
    float l0 = -uu.x, l1 = -uu.y, l2 = -uu.z, l3 = -uu.w;
#pragma unroll
    for (int r = 0; r < 6; r++) {
        float w = wsbp[n * 6 + r];
        h4 t = tb[osb[n * 6 + r]];
        l0 += w * (float)t.x; l1 += w * (float)t.y; l2 += w * (float)t.z; l3 += w * (float)t.w;
    }
#pragma unroll
    for (int r = 0; r < 3; r++) {
        float w = wssp[n * 3 + r];
        h4 t = ts[oss[n * 3 + r]];
        l0 += w * (float)t.x; l1 += w * (float)t.y; l2 += w * (float)t.z; l3 += w * (float)t.w;
    }
    float m = fmaxf(fmaxf(l0, l1), fmaxf(l2, l3));
    float e0 = expf(l0 - m), e1 = expf(l1 - m), e2 = expf(l2 - m), e3 = expf(l3 - m);
    float inv = 1.0f / (e0 + e1 + e2 + e3);
    Qout[n] = make_float4(e0 * inv, e1 * inv, e2 * inv, e3 * inv);
}

// ---------------- fallback (fp32 atomic splat path, R1 behavior) ----------------
template <int D1>
__global__ void k_splat1(const float* __restrict__ ws, const int* __restrict__ os,
                         float* __restrict__ table) {
    int n = blockIdx.x * BLK + threadIdx.x;
    if (n >= NPIX) return;
#pragma unroll
    for (int r = 0; r < D1; r++) atomicAdd(&table[os[n * D1 + r]], ws[n * D1 + r]);
}

template <int D1>
__global__ void k_splat4(const float4* __restrict__ Q, const float* __restrict__ ws,
                         const int* __restrict__ os, float* __restrict__ table) {
    int n = blockIdx.x * BLK + threadIdx.x;
    if (n >= NPIX) return;
    float4 q = Q[n];
#pragma unroll
    for (int r = 0; r < D1; r++) {
        float w = ws[n * D1 + r];
        int o = os[n * D1 + r];
        float* t = table + 4 * (size_t)o;
        atomicAdd(t + 0, q.x * w);
        atomicAdd(t + 1, q.y * w);
        atomicAdd(t + 2, q.z * w);
        atomicAdd(t + 3, q.w * w);
    }
}

__global__ void k_blur4(const float4* __restrict__ in, float4* __restrict__ out,
                        const int* __restrict__ bn, int M) {
    int i = blockIdx.x * BLK + threadIdx.x;
    if (i > M) return;
    if (i == 0) { out[0] = f4zero(); return; }
    int n1 = bn[(size_t)(i - 1) * 2 + 0];
    int n2 = bn[(size_t)(i - 1) * 2 + 1];
    float4 a = in[i], b = in[n1], c = in[n2];
    out[i] = make_float4(a.x + 0.5f * (b.x + c.x), a.y + 0.5f * (b.y + c.y),
                         a.z + 0.5f * (b.z + c.z), a.w + 0.5f * (b.w + c.w));
}

template <int D1>
__global__ void k_norm_slice(const float* __restrict__ table, const float* __restrict__ ws,
                             const int* __restrict__ os, float alpha,
                             float* __restrict__ inv_out) {
    int n = blockIdx.x * BLK + threadIdx.x;
    if (n >= NPIX) return;
    float s = 0.f;
#pragma unroll
    for (int r = 0; r < D1; r++) s += ws[n * D1 + r] * table[os[n * D1 + r]];
    inv_out[n] = 1.0f / (alpha * s + 1e-20f);
}

__global__ void k_slice_combine(const float4* __restrict__ u,
                                const float4* __restrict__ tb, const float* __restrict__ wsb,
                                const int* __restrict__ osb,
                                const float4* __restrict__ ts, const float* __restrict__ wss,
                                const int* __restrict__ oss,
                                const float* __restrict__ inv_nb,
                                const float* __restrict__ inv_ns,
                                float4* __restrict__ Qout) {
    int n = blockIdx.x * BLK + threadIdx.x;
    if (n >= NPIX) return;
    float4 ab = f4zero();
#pragma unroll
    for (int r = 0; r < 6; r++) {
        float w = wsb[n * 6 + r];
        float4 t = tb[osb[n * 6 + r]];
        ab.x += w * t.x; ab.y += w * t.y; ab.z += w * t.z; ab.w += w * t.w;
    }
    float4 as = f4zero();
#pragma unroll
    for (int r = 0; r < 3; r++) {
        float w = wss[n * 3 + r];
        float4 t = ts[oss[n * 3 + r]];
        as.x += w * t.x; as.y += w * t.y; as.z += w * t.z; as.w += w * t.w;
    }
    float cb = BI_COMPAT * ALPHA_B * inv_nb[n];
    float cs = SP_COMPAT * ALPHA_S * inv_ns[n];
    float4 uu = u[n];
    float l0 = -uu.x + cb * ab.x + cs * as.x;
    float l1 = -uu.y + cb * ab.y + cs * as.y;
    float l2 = -uu.z + cb * ab.z + cs * as.z;
    float l3 = -uu.w + cb * ab.w + cs * as.w;
    float m = fmaxf(fmaxf(l0, l1), fmaxf(l2, l3));
    float e0 = expf(l0 - m), e1 = expf(l1 - m), e2 = expf(l2 - m), e3 = expf(l3 - m);
    float inv = 1.0f / (e0 + e1 + e2 + e3);
    Qout[n] = make_float4(e0 * inv, e1 * inv, e2 * inv, e3 * inv);
}

extern "C" void kernel_launch(void* const* d_in, const int* in_sizes, int n_in,
                              void* d_out, int out_size, void* d_ws, size_t ws_size,
                              hipStream_t stream) {
    const float* unary = (const float*)d_in[0];
    const float* wsb   = (const float*)d_in[1];
    const int*   osb   = (const int*)d_in[2];
    const int*   bnb   = (const int*)d_in[3];
    const float* wss   = (const float*)d_in[5];
    const int*   oss   = (const int*)d_in[6];
    const int*   bns   = (const int*)d_in[7];
    const int Mb = in_sizes[3] / 12;   // bn_b is (6, Mb, 2)
    const int Ms = in_sizes[7] / 6;    // bn_s is (3, Ms, 2)
    const int Vb = Mb + 1, Vs = Ms + 1;
    const int totB = NPIX * 6, totS = NPIX * 3;

    float* Q = (float*)d_out;  // N x 4, final value IS the output

    char* p = (char*)d_ws;
    auto alloc = [&](size_t nbytes) -> void* {
        void* r = (void*)p;
        p += (nbytes + 15) & ~(size_t)15;
        return r;
    };
    h4*   tAb  = (h4*)alloc((size_t)Vb * 8);
    h4*   tBb  = (h4*)alloc((size_t)Vb * 8);
    h4*   tAs  = (h4*)alloc((size_t)Vs * 8);
    h4*   tBs  = (h4*)alloc((size_t)Vs * 8);
    float* nAb = (float*)alloc((size_t)Vb * 4);
    float* nBb = (float*)alloc((size_t)Vb * 4);
    float* nAs = (float*)alloc((size_t)Vs * 4);
    float* nBs = (float*)alloc((size_t)Vs * 4);
    float* wsbp = (float*)alloc((size_t)NPIX * 6 * 4);
    float* wssp = (float*)alloc((size_t)NPIX * 3 * 4);
    int*  startB  = (int*)alloc((size_t)Vb * 4);
    int*  cursorB = (int*)alloc((size_t)Vb * 4);
    int2* entB    = (int2*)alloc((size_t)totB * 8);
    int*  startS  = (int*)alloc((size_t)Vs * 4);
    int*  cursorS = (int*)alloc((size_t)Vs * 4);
    int2* entS    = (int2*)alloc((size_t)totS * 8);
    int*  csum    = (int*)alloc(8192 * 4);
    size_t need = (size_t)(p - (char*)d_ws);
    bool use_gather = need <= ws_size;

    dim3 blk(BLK);
    dim3 gN((NPIX + BLK - 1) / BLK);
    dim3 gVb((Vb + BLK - 1) / BLK);
    dim3 gVBS((Vb + Vs + BLK - 1) / BLK);

    if (use_gather) {
        // ---- build CSR inverted indices (both lattices) ----
        int nchB = (Vb + SCAN_CHUNK - 1) / SCAN_CHUNK;
        int nchS = (Vs + SCAN_CHUNK - 1) / SCAN_CHUNK;
        hipMemsetAsync(cursorB, 0, (size_t)Vb * 4, stream);
        hipMemsetAsync(cursorS, 0, (size_t)Vs * 4, stream);
        k_count_both<<<gN, blk, 0, stream>>>(osb, oss, cursorB, cursorS);
        k_chunk_sum<<<dim3(nchB), dim3(SCAN_T), 0, stream>>>(cursorB, Vb, csum);
        k_scan_csum<<<dim3(1), dim3(SCAN_T), 0, stream>>>(csum, nchB);
        k_chunk_scan<<<dim3(nchB), dim3(SCAN_T), 0, stream>>>(cursorB, Vb, csum, startB, cursorB);
        k_chunk_sum<<<dim3(nchS), dim3(SCAN_T), 0, stream>>>(cursorS, Vs, csum);
        k_scan_csum<<<dim3(1), dim3(SCAN_T), 0, stream>>>(csum, nchS);
        k_chunk_scan<<<dim3(nchS), dim3(SCAN_T), 0, stream>>>(cursorS, Vs, csum, startS, cursorS);
        k_fill_both<<<gN, blk, 0, stream>>>(osb, wsb, cursorB, entB, oss, wss, cursorS, entS);

        // ---- normalizers (fp32, C=1), then prescale slice weights ----
        k_gather1_both<<<gVBS, blk, 0, stream>>>(entB, startB, totB, Vb, nAb,
                                                 entS, startS, totS, Vs, nAs);
        {
            float* a = nAb; float* b = nBb;
            float* as_ = nAs; float* bs_ = nBs;
            for (int j = 0; j < 3; j++) {
                k_blur1_both<<<gVBS, blk, 0, stream>>>(a, b, bnb + (size_t)j * Mb * 2, Mb,
                                                       as_, bs_, bns + (size_t)j * Ms * 2, Ms);
                float* t = a; a = b; b = t;
                t = as_; as_ = bs_; bs_ = t;
            }
            for (int j = 3; j < 6; j++) {
                k_blur1<<<gVb, blk, 0, stream>>>(a, b, bnb + (size_t)j * Mb * 2, Mb);
                float* t = a; a = b; b = t;
            }
            // bilateral final in a (= nAb), spatial final in as_ (= nBs)
            k_norm_prescale<<<gN, blk, 0, stream>>>(a, wsb, osb, as_, wss, oss, wsbp, wssp);
        }

        // ---- Q0 = softmax(-u) ----
        k_softmax_init<<<gN, blk, 0, stream>>>((const float4*)unary, (float4*)Q);

        // ---- 10 mean-field iterations ----
        for (int it = 0; it < 10; it++) {
            k_gather4h_both<<<gVBS, blk, 0, stream>>>(entB, startB, totB, Vb, tAb,
                                                      entS, startS, totS, Vs, tAs,
                                                      (const float4*)Q);
            h4* a = tAb; h4* b = tBb;
            h4* as_ = tAs; h4* bs_ = tBs;
            for (int j = 0; j < 3; j++) {
                k_blur4h_both<<<gVBS, blk, 0, stream>>>(a, b, bnb + (size_t)j * Mb * 2, Mb,
                                                        as_, bs_, bns + (size_t)j * Ms * 2, Ms);
                h4* t = a; a = b; b = t;
                t = as_; as_ = bs_; bs_ = t;
            }
            for (int j = 3; j < 6; j++) {
                k_blur4h<<<gVb, blk, 0, stream>>>(a, b, bnb + (size_t)j * Mb * 2, Mb);
                h4* t = a; a = b; b = t;
            }
            // bilateral final in a (= tAb), spatial final in as_ (= tBs)
            k_slice_combine_h<<<gN, blk, 0, stream>>>((const float4*)unary,
                                                      a, wsbp, osb, as_, wssp, oss,
                                                      (float4*)Q);
        }
    } else {
        // ---- fallback: fp32 atomic splat path ----
        char* q = (char*)d_ws;
        auto alloc2 = [&](size_t nbytes) -> void* {
            void* r = (void*)q;
            q += (nbytes + 15) & ~(size_t)15;
            return r;
        };
        float* fAb = (float*)alloc2((size_t)Vb * 4 * sizeof(float));
        float* fBb = (float*)alloc2((size_t)Vb * 4 * sizeof(float));
        float* fAs = (float*)alloc2((size_t)Vs * 4 * sizeof(float));
        float* fBs = (float*)alloc2((size_t)Vs * 4 * sizeof(float));
        float* inv_nb = (float*)alloc2(NPIX * sizeof(float));
        float* inv_ns = (float*)alloc2(NPIX * sizeof(float));
        dim3 gMb((Mb + 1 + BLK - 1) / BLK);
        dim3 gMs((Ms + 1 + BLK - 1) / BLK);

        hipMemsetAsync(fAb, 0, (size_t)Vb * sizeof(float), stream);
        k_splat1<6><<<gN, blk, 0, stream>>>(wsb, osb, fAb);
        {
            float* a = fAb; float* b = fBb;
            for (int j = 0; j < 6; j++) {
                k_blur1<<<gMb, blk, 0, stream>>>(a, b, bnb + (size_t)j * Mb * 2, Mb);
                float* t = a; a = b; b = t;
            }
            k_norm_slice<6><<<gN, blk, 0, stream>>>(a, wsb, osb, ALPHA_B, inv_nb);
        }
        hipMemsetAsync(fAs, 0, (size_t)Vs * sizeof(float), stream);
        k_splat1<3><<<gN, blk, 0, stream>>>(wss, oss, fAs);
        {
            float* a = fAs; float* b = fBs;
            for (int j = 0; j < 3; j++) {
                k_blur1<<<gMs, blk, 0, stream>>>(a, b, bns + (size_t)j * Ms * 2, Ms);
                float* t = a; a = b; b = t;
            }
            k_norm_slice<3><<<gN, blk, 0, stream>>>(a, wss, oss, ALPHA_S, inv_ns);
        }
        k_softmax_init<<<gN, blk, 0, stream>>>((const float4*)unary, (float4*)Q);
        for (int it = 0; it < 10; it++) {
            hipMemsetAsync(fAb, 0, (size_t)Vb * 4 * sizeof(float), stream);
            k_splat4<6><<<gN, blk, 0, stream>>>((const float4*)Q, wsb, osb, fAb);
            float* a = fAb; float* b = fBb;
            for (int j = 0; j < 6; j++) {
                k_blur4<<<gMb, blk, 0, stream>>>((const float4*)a, (float4*)b,
                                                 bnb + (size_t)j * Mb * 2, Mb);
                float* t = a; a = b; b = t;
            }
            float* finb = a;
            hipMemsetAsync(fAs, 0, (size_t)Vs * 4 * sizeof(float), stream);
            k_splat4<3><<<gN, blk, 0, stream>>>((const float4*)Q, wss, oss, fAs);
            float* as_ = fAs; float* bs_ = fBs;
            for (int j = 0; j < 3; j++) {
                k_blur4<<<gMs, blk, 0, stream>>>((const float4*)as_, (float4*)bs_,
                                                 bns + (size_t)j * Ms * 2, Ms);
                float* t = as_; as_ = bs_; bs_ = t;
            }
            float* fins = as_;
            k_slice_combine<<<gN, blk, 0, stream>>>((const float4*)unary,
                                                    (const float4*)finb, wsb, osb,
                                                    (const float4*)fins, wss, oss,
                                                    inv_nb, inv_ns, (float4*)Q);
        }
    }
}

// Round 4
// 1010.257 us; speedup vs baseline: 6.6863x; 1.0890x over previous
//
#include <hip/hip_runtime.h>

#define NPIX (512 * 512)
#define BLK 256

#define SCAN_T 256
#define SCAN_E 8
#define SCAN_CHUNK (SCAN_T * SCAN_E)  // 2048

typedef _Float16 h4 __attribute__((ext_vector_type(4)));

constexpr float ALPHA_B = 32.0f / 33.0f;   // 1/(1+2^-5)
constexpr float ALPHA_S = 0.8f;            // 1/(1+2^-2)
constexpr float BI_COMPAT = 10.0f;
constexpr float SP_COMPAT = 3.0f;

// 4-byte CSR entry: [31:18] = weight (14-bit fixed point, /16383), [17:0] = pixel id
__device__ __forceinline__ unsigned pack_ent(int n, float w) {
    float wc = fminf(fmaxf(w, 0.f), 1.f);
    unsigned iw = (unsigned)(wc * 16383.f + 0.5f);
    return (iw << 18) | (unsigned)n;
}
__device__ __forceinline__ int ent_pix(unsigned e) { return (int)(e & 0x3FFFFu); }
__device__ __forceinline__ float ent_w(unsigned e) {
    return (float)(e >> 18) * (1.0f / 16383.0f);
}

__device__ __forceinline__ float4 f4zero() { return make_float4(0.f, 0.f, 0.f, 0.f); }
__device__ __forceinline__ h4 h4zero() {
    h4 z; z.x = (_Float16)0.f; z.y = (_Float16)0.f; z.z = (_Float16)0.f; z.w = (_Float16)0.f;
    return z;
}

// ---------------- softmax init (fallback path) ----------------
__global__ void k_softmax_init(const float4* __restrict__ u, float4* __restrict__ Q) {
    int n = blockIdx.x * BLK + threadIdx.x;
    if (n >= NPIX) return;
    float4 uu = u[n];
    float l0 = -uu.x, l1 = -uu.y, l2 = -uu.z, l3 = -uu.w;
    float m = fmaxf(fmaxf(l0, l1), fmaxf(l2, l3));
    float e0 = expf(l0 - m), e1 = expf(l1 - m), e2 = expf(l2 - m), e3 = expf(l3 - m);
    float inv = 1.0f / (e0 + e1 + e2 + e3);
    Q[n] = make_float4(e0 * inv, e1 * inv, e2 * inv, e3 * inv);
}

// ---------------- fused count + softmax init ----------------
__global__ void k_count_softmax(const int* __restrict__ osb, const int* __restrict__ oss,
                                int* __restrict__ cntB, int* __restrict__ cntS,
                                const float4* __restrict__ u, float4* __restrict__ Q) {
    int n = blockIdx.x * BLK + threadIdx.x;
    if (n >= NPIX) return;
    float4 uu = u[n];
    float l0 = -uu.x, l1 = -uu.y, l2 = -uu.z, l3 = -uu.w;
    float m = fmaxf(fmaxf(l0, l1), fmaxf(l2, l3));
    float e0 = expf(l0 - m), e1 = expf(l1 - m), e2 = expf(l2 - m), e3 = expf(l3 - m);
    float inv = 1.0f / (e0 + e1 + e2 + e3);
    Q[n] = make_float4(e0 * inv, e1 * inv, e2 * inv, e3 * inv);
#pragma unroll
    for (int r = 0; r < 6; r++) atomicAdd(&cntB[osb[n * 6 + r]], 1);
#pragma unroll
    for (int r = 0; r < 3; r++) atomicAdd(&cntS[oss[n * 3 + r]], 1);
}

// ---------------- scan ----------------
__global__ void k_chunk_sum(const int* __restrict__ counts, int V, int* __restrict__ csum) {
    __shared__ int lds[SCAN_T];
    int base = blockIdx.x * SCAN_CHUNK;
    int s = 0;
#pragma unroll
    for (int j = 0; j < SCAN_E; j++) {
        int idx = base + threadIdx.x * SCAN_E + j;
        if (idx < V) s += counts[idx];
    }
    lds[threadIdx.x] = s;
    __syncthreads();
    for (int off = SCAN_T / 2; off > 0; off >>= 1) {
        if ((int)threadIdx.x < off) lds[threadIdx.x] += lds[threadIdx.x + off];
        __syncthreads();
    }
    if (threadIdx.x == 0) csum[blockIdx.x] = lds[0];
}

__global__ void k_scan_csum(int* __restrict__ csum, int nchunks) {
    __shared__ int lds[SCAN_T];
    int carry = 0;
    for (int base = 0; base < nchunks; base += SCAN_T) {
        int idx = base + threadIdx.x;
        int v = (idx < nchunks) ? csum[idx] : 0;
        lds[threadIdx.x] = v;
        __syncthreads();
        for (int off = 1; off < SCAN_T; off <<= 1) {
            int t = ((int)threadIdx.x >= off) ? lds[threadIdx.x - off] : 0;
            __syncthreads();
            lds[threadIdx.x] += t;
            __syncthreads();
        }
        int incl = lds[threadIdx.x];
        int tile_total = lds[SCAN_T - 1];
        if (idx < nchunks) csum[idx] = incl - v + carry;  // exclusive
        carry += tile_total;
        __syncthreads();
    }
}

// writes BOTH start[] and cursor[]
__global__ void k_chunk_scan(const int* __restrict__ counts, int V,
                             const int* __restrict__ csum, int* __restrict__ start,
                             int* __restrict__ cursor) {
    __shared__ int lds[SCAN_T];
    int base = blockIdx.x * SCAN_CHUNK;
    int local[SCAN_E];
    int s = 0;
#pragma unroll
    for (int j = 0; j < SCAN_E; j++) {
        int idx = base + threadIdx.x * SCAN_E + j;
        int c = (idx < V) ? counts[idx] : 0;
        local[j] = c;
        s += c;
    }
    lds[threadIdx.x] = s;
    __syncthreads();
    for (int off = 1; off < SCAN_T; off <<= 1) {
        int t = ((int)threadIdx.x >= off) ? lds[threadIdx.x - off] : 0;
        __syncthreads();
        lds[threadIdx.x] += t;
        __syncthreads();
    }
    int excl = lds[threadIdx.x] - s + csum[blockIdx.x];
#pragma unroll
    for (int j = 0; j < SCAN_E; j++) {
        int idx = base + threadIdx.x * SCAN_E + j;
        if (idx < V) { start[idx] = excl; cursor[idx] = excl; }
        excl += local[j];
    }
}

__global__ void k_fill_both(const int* __restrict__ osb, const float* __restrict__ wsb,
                            int* __restrict__ curB, unsigned* __restrict__ entB,
                            const int* __restrict__ oss, const float* __restrict__ wss,
                            int* __restrict__ curS, unsigned* __restrict__ entS) {
    int n = blockIdx.x * BLK + threadIdx.x;
    if (n >= NPIX) return;
#pragma unroll
    for (int r = 0; r < 6; r++) {
        int o = osb[n * 6 + r];
        int pos = atomicAdd(&curB[o], 1);
        entB[pos] = pack_ent(n, wsb[n * 6 + r]);
    }
#pragma unroll
    for (int r = 0; r < 3; r++) {
        int o = oss[n * 3 + r];
        int pos = atomicAdd(&curS[o], 1);
        entS[pos] = pack_ent(n, wss[n * 3 + r]);
    }
}

// ---------------- gather-based splat ----------------
__global__ void k_gather1_both(const unsigned* __restrict__ entB, const int* __restrict__ startB,
                               int totB, int Vb, float* __restrict__ nB,
                               const unsigned* __restrict__ entS, const int* __restrict__ startS,
                               int totS, int Vs, float* __restrict__ nS) {
    int i = blockIdx.x * BLK + threadIdx.x;
    const unsigned* ent; const int* st; int tot, V, idx; float* out;
    if (i < Vb) { ent = entB; st = startB; tot = totB; V = Vb; out = nB; idx = i; }
    else {
        idx = i - Vb;
        if (idx >= Vs) return;
        ent = entS; st = startS; tot = totS; V = Vs; out = nS;
    }
    int s = st[idx];
    int e = (idx + 1 < V) ? st[idx + 1] : tot;
    float acc = 0.f;
    for (int k = s; k < e; k++) acc += ent_w(ent[k]);
    out[idx] = acc;
}

__global__ void k_gather4h_both(const unsigned* __restrict__ entB, const int* __restrict__ startB,
                                int totB, int Vb, h4* __restrict__ tB,
                                const unsigned* __restrict__ entS, const int* __restrict__ startS,
                                int totS, int Vs, h4* __restrict__ tS,
                                const float4* __restrict__ Q) {
    int i = blockIdx.x * BLK + threadIdx.x;
    const unsigned* ent; const int* st; int tot, V, idx; h4* out;
    if (i < Vb) { ent = entB; st = startB; tot = totB; V = Vb; out = tB; idx = i; }
    else {
        idx = i - Vb;
        if (idx >= Vs) return;
        ent = entS; st = startS; tot = totS; V = Vs; out = tS;
    }
    int s = st[idx];
    int e = (idx + 1 < V) ? st[idx + 1] : tot;
    float ax = 0.f, ay = 0.f, az = 0.f, aw = 0.f;
    for (int k = s; k < e; k++) {
        unsigned en = ent[k];
        float w = ent_w(en);
        float4 q = Q[ent_pix(en)];
        ax += w * q.x; ay += w * q.y; az += w * q.z; aw += w * q.w;
    }
    h4 h;
    h.x = (_Float16)ax; h.y = (_Float16)ay; h.z = (_Float16)az; h.w = (_Float16)aw;
    out[idx] = h;
}

// ---------------- blur ----------------
__global__ void k_blur1(const float* __restrict__ in, float* __restrict__ out,
                        const int* __restrict__ bn, int M) {
    int i = blockIdx.x * BLK + threadIdx.x;
    if (i > M) return;
    if (i == 0) { out[0] = 0.f; return; }
    int n1 = bn[(size_t)(i - 1) * 2 + 0];
    int n2 = bn[(size_t)(i - 1) * 2 + 1];
    out[i] = in[i] + 0.5f * (in[n1] + in[n2]);
}

__global__ void k_blur1_both(const float* __restrict__ inB, float* __restrict__ outB,
                             const int* __restrict__ bnB, int Mb,
                             const float* __restrict__ inS, float* __restrict__ outS,
                             const int* __restrict__ bnS, int Ms) {
    int i = blockIdx.x * BLK + threadIdx.x;
    const float* in; float* out; const int* bn; int M, idx;
    if (i <= Mb) { in = inB; out = outB; bn = bnB; M = Mb; idx = i; }
    else {
        idx = i - (Mb + 1);
        if (idx > Ms) return;
        in = inS; out = outS; bn = bnS; M = Ms;
    }
    if (idx == 0) { out[0] = 0.f; return; }
    int n1 = bn[(size_t)(idx - 1) * 2 + 0];
    int n2 = bn[(size_t)(idx - 1) * 2 + 1];
    out[idx] = in[idx] + 0.5f * (in[n1] + in[n2]);
}

__global__ void k_blur4h(const h4* __restrict__ in, h4* __restrict__ out,
                         const int* __restrict__ bn, int M) {
    int i = blockIdx.x * BLK + threadIdx.x;
    if (i > M) return;
    if (i == 0) { out[0] = h4zero(); return; }
    int n1 = bn[(size_t)(i - 1) * 2 + 0];
    int n2 = bn[(size_t)(i - 1) * 2 + 1];
    h4 a = in[i], b = in[n1], c = in[n2];
    h4 o;
    o.x = (_Float16)((float)a.x + 0.5f * ((float)b.x + (float)c.x));
    o.y = (_Float16)((float)a.y + 0.5f * ((float)b.y + (float)c.y));
    o.z = (_Float16)((float)a.z + 0.5f * ((float)b.z + (float)c.z));
    o.w = (_Float16)((float)a.w + 0.5f * ((float)b.w + (float)c.w));
    out[i] = o;
}

__global__ void k_blur4h_both(const h4* __restrict__ inB, h4* __restrict__ outB,
                              const int* __restrict__ bnB, int Mb,
                              const h4* __restrict__ inS, h4* __restrict__ outS,
                              const int* __restrict__ bnS, int Ms) {
    int i = blockIdx.x * BLK + threadIdx.x;
    const h4* in; h4* out; const int* bn; int M, idx;
    if (i <= Mb) { in = inB; out = outB; bn = bnB; M = Mb; idx = i; }
    else {
        idx = i - (Mb + 1);
        if (idx > Ms) return;
        in = inS; out = outS; bn = bnS; M = Ms;
    }
    if (idx == 0) { out[0] = h4zero(); return; }
    int n1 = bn[(size_t)(idx - 1) * 2 + 0];
    int n2 = bn[(size_t)(idx - 1) * 2 + 1];
    h4 a = in[idx], b = in[n1], c = in[n2];
    h4 o;
    o.x = (_Float16)((float)a.x + 0.5f * ((float)b.x + (float)c.x));
    o.y = (_Float16)((float)a.y + 0.5f * ((float)b.y + (float)c.y));
    o.z = (_Float16)((float)a.z + 0.5f * ((float)b.z + (float)c.z));
    o.w = (_Float16)((float)a.w + 0.5f * ((float)b.w + (float)c.w));
    out[idx] = o;
}

// ---------------- normalizer slice + weight prescale ----------------
__global__ void k_norm_prescale(const float* __restrict__ nTb, const float* __restrict__ wsb,
                                const int* __restrict__ osb,
                                const float* __restrict__ nTs, const float* __restrict__ wss,
                                const int* __restrict__ oss,
                                float* __restrict__ wsbp, float* __restrict__ wssp) {
    int n = blockIdx.x * BLK + threadIdx.x;
    if (n >= NPIX) return;
    float sb = 0.f;
#pragma unroll
    for (int r = 0; r < 6; r++) sb += wsb[n * 6 + r] * nTb[osb[n * 6 + r]];
    float cb = BI_COMPAT * ALPHA_B / (ALPHA_B * sb + 1e-20f);
#pragma unroll
    for (int r = 0; r < 6; r++) wsbp[n * 6 + r] = wsb[n * 6 + r] * cb;
    float ss = 0.f;
#pragma unroll
    for (int r = 0; r < 3; r++) ss += wss[n * 3 + r] * nTs[oss[n * 3 + r]];
    float cs = SP_COMPAT * ALPHA_S / (ALPHA_S * ss + 1e-20f);
#pragma unroll
    for (int r = 0; r < 3; r++) wssp[n * 3 + r] = wss[n * 3 + r] * cs;
}

// ---------------- fused slice + message + softmax ----------------
__global__ void k_slice_combine_h(const float4* __restrict__ u,
                                  const h4* __restrict__ tb, const float* __restrict__ wsbp,
                                  const int* __restrict__ osb,
                                  const h4* __restrict__ ts, const float* __restrict__ wssp,
                                  const int* __restrict__ oss,
                                  float4* __restrict__ Qout) {
    int n = blockIdx.x * BLK + threadIdx.x;
    if (n >= NPIX) return;
    float4 uu = u[n];
    float l0 = -uu.x, l1 = -uu.y, l2 = -uu.z, l3 = -uu.w;
#pragma unroll
    for (int r = 0; r < 6; r++) {
        float w = wsbp[n * 6 + r];
        h4 t = tb[osb[n * 6 + r]];
        l0 += w * (float)t.x; l1 += w * (float)t.y; l2 += w * (float)t.z; l3 += w * (float)t.w;
    }
#pragma unroll
    for (int r = 0; r < 3; r++) {
        float w = wssp[n * 3 + r];
        h4 t = ts[oss[n * 3 + r]];
        l0 += w * (float)t.x; l1 += w * (float)t.y; l2 += w * (float)t.z; l3 += w * (float)t.w;
    }
    float m = fmaxf(fmaxf(l0, l1), fmaxf(l2, l3));
    float e0 = expf(l0 - m), e1 = expf(l1 - m), e2 = expf(l2 - m), e3 = expf(l3 - m);
    float inv = 1.0f / (e0 + e1 + e2 + e3);
    Qout[n] = make_float4(e0 * inv, e1 * inv, e2 * inv, e3 * inv);
}

// ---------------- fallback (fp32 atomic splat path) ----------------
template <int D1>
__global__ void k_splat1(const float* __restrict__ ws, const int* __restrict__ os,
                         float* __restrict__ table) {
    int n = blockIdx.x * BLK + threadIdx.x;
    if (n >= NPIX) return;
#pragma unroll
    for (int r = 0; r < D1; r++) atomicAdd(&table[os[n * D1 + r]], ws[n * D1 + r]);
}

template <int D1>
__global__ void k_splat4(const float4* __restrict__ Q, const float* __restrict__ ws,
                         const int* __restrict__ os, float* __restrict__ table) {
    int n = blockIdx.x * BLK + threadIdx.x;
    if (n >= NPIX) return;
    float4 q = Q[n];
#pragma unroll
    for (int r = 0; r < D1; r++) {
        float w = ws[n * D1 + r];
        int o = os[n * D1 + r];
        float* t = table + 4 * (size_t)o;
        atomicAdd(t + 0, q.x * w);
        atomicAdd(t + 1, q.y * w);
        atomicAdd(t + 2, q.z * w);
        atomicAdd(t + 3, q.w * w);
    }
}

__global__ void k_blur4(const float4* __restrict__ in, float4* __restrict__ out,
                        const int* __restrict__ bn, int M) {
    int i = blockIdx.x * BLK + threadIdx.x;
    if (i > M) return;
    if (i == 0) { out[0] = f4zero(); return; }
    int n1 = bn[(size_t)(i - 1) * 2 + 0];
    int n2 = bn[(size_t)(i - 1) * 2 + 1];
    float4 a = in[i], b = in[n1], c = in[n2];
    out[i] = make_float4(a.x + 0.5f * (b.x + c.x), a.y + 0.5f * (b.y + c.y),
                         a.z + 0.5f * (b.z + c.z), a.w + 0.5f * (b.w + c.w));
}

template <int D1>
__global__ void k_norm_slice(const float* __restrict__ table, const float* __restrict__ ws,
                             const int* __restrict__ os, float alpha,
                             float* __restrict__ inv_out) {
    int n = blockIdx.x * BLK + threadIdx.x;
    if (n >= NPIX) return;
    float s = 0.f;
#pragma unroll
    for (int r = 0; r < D1; r++) s += ws[n * D1 + r] * table[os[n * D1 + r]];
    inv_out[n] = 1.0f / (alpha * s + 1e-20f);
}

__global__ void k_slice_combine(const float4* __restrict__ u,
                                const float4* __restrict__ tb, const float* __restrict__ wsb,
                                const int* __restrict__ osb,
                                const float4* __restrict__ ts, const float* __restrict__ wss,
                                const int* __restrict__ oss,
                                const float* __restrict__ inv_nb,
                                const float* __restrict__ inv_ns,
                                float4* __restrict__ Qout) {
    int n = blockIdx.x * BLK + threadIdx.x;
    if (n >= NPIX) return;
    float4 ab = f4zero();
#pragma unroll
    for (int r = 0; r < 6; r++) {
        float w = wsb[n * 6 + r];
        float4 t = tb[osb[n * 6 + r]];
        ab.x += w * t.x; ab.y += w * t.y; ab.z += w * t.z; ab.w += w * t.w;
    }
    float4 as = f4zero();
#pragma unroll
    for (int r = 0; r < 3; r++) {
        float w = wss[n * 3 + r];
        float4 t = ts[oss[n * 3 + r]];
        as.x += w * t.x; as.y += w * t.y; as.z += w * t.z; as.w += w * t.w;
    }
    float cb = BI_COMPAT * ALPHA_B * inv_nb[n];
    float cs = SP_COMPAT * ALPHA_S * inv_ns[n];
    float4 uu = u[n];
    float l0 = -uu.x + cb * ab.x + cs * as.x;
    float l1 = -uu.y + cb * ab.y + cs * as.y;
    float l2 = -uu.z + cb * ab.z + cs * as.z;
    float l3 = -uu.w + cb * ab.w + cs * as.w;
    float m = fmaxf(fmaxf(l0, l1), fmaxf(l2, l3));
    float e0 = expf(l0 - m), e1 = expf(l1 - m), e2 = expf(l2 - m), e3 = expf(l3 - m);
    float inv = 1.0f / (e0 + e1 + e2 + e3);
    Qout[n] = make_float4(e0 * inv, e1 * inv, e2 * inv, e3 * inv);
}

extern "C" void kernel_launch(void* const* d_in, const int* in_sizes, int n_in,
                              void* d_out, int out_size, void* d_ws, size_t ws_size,
                              hipStream_t stream) {
    const float* unary = (const float*)d_in[0];
    const float* wsb   = (const float*)d_in[1];
    const int*   osb   = (const int*)d_in[2];
    const int*   bnb   = (const int*)d_in[3];
    const float* wss   = (const float*)d_in[5];
    const int*   oss   = (const int*)d_in[6];
    const int*   bns   = (const int*)d_in[7];
    const int Mb = in_sizes[3] / 12;   // bn_b is (6, Mb, 2)
    const int Ms = in_sizes[7] / 6;    // bn_s is (3, Ms, 2)
    const int Vb = Mb + 1, Vs = Ms + 1;
    const int totB = NPIX * 6, totS = NPIX * 3;

    float* Q = (float*)d_out;  // N x 4, final value IS the output

    char* p = (char*)d_ws;
    auto alloc = [&](size_t nbytes) -> void* {
        void* r = (void*)p;
        p += (nbytes + 15) & ~(size_t)15;
        return r;
    };
    h4*   tAb  = (h4*)alloc((size_t)Vb * 8);
    h4*   tBb  = (h4*)alloc((size_t)Vb * 8);
    h4*   tAs  = (h4*)alloc((size_t)Vs * 8);
    h4*   tBs  = (h4*)alloc((size_t)Vs * 8);
    float* nAb = (float*)alloc((size_t)Vb * 4);
    float* nBb = (float*)alloc((size_t)Vb * 4);
    float* nAs = (float*)alloc((size_t)Vs * 4);
    float* nBs = (float*)alloc((size_t)Vs * 4);
    float* wsbp = (float*)alloc((size_t)NPIX * 6 * 4);
    float* wssp = (float*)alloc((size_t)NPIX * 3 * 4);
    int*  startB  = (int*)alloc((size_t)Vb * 4);
    int*  cursorB = (int*)alloc((size_t)Vb * 4);
    unsigned* entB = (unsigned*)alloc((size_t)totB * 4);
    int*  startS  = (int*)alloc((size_t)Vs * 4);
    int*  cursorS = (int*)alloc((size_t)Vs * 4);
    unsigned* entS = (unsigned*)alloc((size_t)totS * 4);
    int*  csum    = (int*)alloc(8192 * 4);
    size_t need = (size_t)(p - (char*)d_ws);
    bool use_gather = need <= ws_size;

    dim3 blk(BLK);
    dim3 gN((NPIX + BLK - 1) / BLK);
    dim3 gVb((Vb + BLK - 1) / BLK);
    dim3 gVBS((Vb + Vs + BLK - 1) / BLK);

    if (use_gather) {
        // ---- build CSR inverted indices (both lattices) + softmax init ----
        int nchB = (Vb + SCAN_CHUNK - 1) / SCAN_CHUNK;
        int nchS = (Vs + SCAN_CHUNK - 1) / SCAN_CHUNK;
        hipMemsetAsync(cursorB, 0, (size_t)Vb * 4, stream);
        hipMemsetAsync(cursorS, 0, (size_t)Vs * 4, stream);
        k_count_softmax<<<gN, blk, 0, stream>>>(osb, oss, cursorB, cursorS,
                                                (const float4*)unary, (float4*)Q);
        k_chunk_sum<<<dim3(nchB), dim3(SCAN_T), 0, stream>>>(cursorB, Vb, csum);
        k_scan_csum<<<dim3(1), dim3(SCAN_T), 0, stream>>>(csum, nchB);
        k_chunk_scan<<<dim3(nchB), dim3(SCAN_T), 0, stream>>>(cursorB, Vb, csum, startB, cursorB);
        k_chunk_sum<<<dim3(nchS), dim3(SCAN_T), 0, stream>>>(cursorS, Vs, csum);
        k_scan_csum<<<dim3(1), dim3(SCAN_T), 0, stream>>>(csum, nchS);
        k_chunk_scan<<<dim3(nchS), dim3(SCAN_T), 0, stream>>>(cursorS, Vs, csum, startS, cursorS);
        k_fill_both<<<gN, blk, 0, stream>>>(osb, wsb, cursorB, entB, oss, wss, cursorS, entS);

        // ---- normalizers (fp32, C=1), then prescale slice weights ----
        k_gather1_both<<<gVBS, blk, 0, stream>>>(entB, startB, totB, Vb, nAb,
                                                 entS, startS, totS, Vs, nAs);
        {
            float* a = nAb; float* b = nBb;
            float* as_ = nAs; float* bs_ = nBs;
            for (int j = 0; j < 3; j++) {
                k_blur1_both<<<gVBS, blk, 0, stream>>>(a, b, bnb + (size_t)j * Mb * 2, Mb,
                                                       as_, bs_, bns + (size_t)j * Ms * 2, Ms);
                float* t = a; a = b; b = t;
                t = as_; as_ = bs_; bs_ = t;
            }
            for (int j = 3; j < 6; j++) {
                k_blur1<<<gVb, blk, 0, stream>>>(a, b, bnb + (size_t)j * Mb * 2, Mb);
                float* t = a; a = b; b = t;
            }
            // bilateral final in a (= nAb), spatial final in as_ (= nBs)
            k_norm_prescale<<<gN, blk, 0, stream>>>(a, wsb, osb, as_, wss, oss, wsbp, wssp);
        }

        // ---- 10 mean-field iterations ----
        for (int it = 0; it < 10; it++) {
            k_gather4h_both<<<gVBS, blk, 0, stream>>>(entB, startB, totB, Vb, tAb,
                                                      entS, startS, totS, Vs, tAs,
                                                      (const float4*)Q);
            h4* a = tAb; h4* b = tBb;
            h4* as_ = tAs; h4* bs_ = tBs;
            for (int j = 0; j < 3; j++) {
                k_blur4h_both<<<gVBS, blk, 0, stream>>>(a, b, bnb + (size_t)j * Mb * 2, Mb,
                                                        as_, bs_, bns + (size_t)j * Ms * 2, Ms);
                h4* t = a; a = b; b = t;
                t = as_; as_ = bs_; bs_ = t;
            }
            for (int j = 3; j < 6; j++) {
                k_blur4h<<<gVb, blk, 0, stream>>>(a, b, bnb + (size_t)j * Mb * 2, Mb);
                h4* t = a; a = b; b = t;
            }
            // bilateral final in a (= tAb), spatial final in as_ (= tBs)
            k_slice_combine_h<<<gN, blk, 0, stream>>>((const float4*)unary,
                                                      a, wsbp, osb, as_, wssp, oss,
                                                      (float4*)Q);
        }
    } else {
        // ---- fallback: fp32 atomic splat path ----
        char* q = (char*)d_ws;
        auto alloc2 = [&](size_t nbytes) -> void* {
            void* r = (void*)q;
            q += (nbytes + 15) & ~(size_t)15;
            return r;
        };
        float* fAb = (float*)alloc2((size_t)Vb * 4 * sizeof(float));
        float* fBb = (float*)alloc2((size_t)Vb * 4 * sizeof(float));
        float* fAs = (float*)alloc2((size_t)Vs * 4 * sizeof(float));
        float* fBs = (float*)alloc2((size_t)Vs * 4 * sizeof(float));
        float* inv_nb = (float*)alloc2(NPIX * sizeof(float));
        float* inv_ns = (float*)alloc2(NPIX * sizeof(float));
        dim3 gMb((Mb + 1 + BLK - 1) / BLK);
        dim3 gMs((Ms + 1 + BLK - 1) / BLK);

        hipMemsetAsync(fAb, 0, (size_t)Vb * sizeof(float), stream);
        k_splat1<6><<<gN, blk, 0, stream>>>(wsb, osb, fAb);
        {
            float* a = fAb; float* b = fBb;
            for (int j = 0; j < 6; j++) {
                k_blur1<<<gMb, blk, 0, stream>>>(a, b, bnb + (size_t)j * Mb * 2, Mb);
                float* t = a; a = b; b = t;
            }
            k_norm_slice<6><<<gN, blk, 0, stream>>>(a, wsb, osb, ALPHA_B, inv_nb);
        }
        hipMemsetAsync(fAs, 0, (size_t)Vs * sizeof(float), stream);
        k_splat1<3><<<gN, blk, 0, stream>>>(wss, oss, fAs);
        {
            float* a = fAs; float* b = fBs;
            for (int j = 0; j < 3; j++) {
                k_blur1<<<gMs, blk, 0, stream>>>(a, b, bns + (size_t)j * Ms * 2, Ms);
                float* t = a; a = b; b = t;
            }
            k_norm_slice<3><<<gN, blk, 0, stream>>>(a, wss, oss, ALPHA_S, inv_ns);
        }
        k_softmax_init<<<gN, blk, 0, stream>>>((const float4*)unary, (float4*)Q);
        for (int it = 0; it < 10; it++) {
            hipMemsetAsync(fAb, 0, (size_t)Vb * 4 * sizeof(float), stream);
            k_splat4<6><<<gN, blk, 0, stream>>>((const float4*)Q, wsb, osb, fAb);
            float* a = fAb; float* b = fBb;
            for (int j = 0; j < 6; j++) {
                k_blur4<<<gMb, blk, 0, stream>>>((const float4*)a, (float4*)b,
                                                 bnb + (size_t)j * Mb * 2, Mb);
                float* t = a; a = b; b = t;
            }
            float* finb = a;
            hipMemsetAsync(fAs, 0, (size_t)Vs * 4 * sizeof(float), stream);
            k_splat4<3><<<gN, blk, 0, stream>>>((const float4*)Q, wss, oss, fAs);
            float* as_ = fAs; float* bs_ = fBs;
            for (int j = 0; j < 3; j++) {
                k_blur4<<<gMs, blk, 0, stream>>>((const float4*)as_, (float4*)bs_,
                                                 bns + (size_t)j * Ms * 2, Ms);
                float* t = as_; as_ = bs_; bs_ = t;
            }
            float* fins = as_;
            k_slice_combine<<<gN, blk, 0, stream>>>((const float4*)unary,
                                                    (const float4*)finb, wsb, osb,
                                                    (const float4*)fins, wss, oss,
                                                    inv_nb, inv_ns, (float4*)Q);
        }
    }
}